// Round 14
// baseline (147.391 us; speedup 1.0000x reference)
//
#include <hip/hip_runtime.h>
#include <cstdint>
#include <cstddef>

#define J 64
#define XD 512
#define HD 1024
#define YD 16
#define PP 8
#define NN 1024

typedef __bf16 bf16;
typedef __attribute__((ext_vector_type(8))) __bf16 bf16x8;
typedef __attribute__((ext_vector_type(4))) __bf16 bf16x4;
typedef __attribute__((ext_vector_type(4))) float f32x4;

__device__ __forceinline__ void gload16(const void* g, void* l) {
  __builtin_amdgcn_global_load_lds((__attribute__((address_space(1))) void*)(g),
                                   (__attribute__((address_space(3))) void*)(l),
                                   16, 0, 0);
}

// ---- K1a: W1T[j][h][x] = bf16(mu_W1[x][h] + e_W1[j][x][h]*sig_W1[x][h])
__global__ __launch_bounds__(256) void build_w1t(
    const float* __restrict__ muW1, const float* __restrict__ sigW1,
    const float* __restrict__ eW1, bf16* __restrict__ W1T) {
  __shared__ bf16 sT[64][66];
  int b = blockIdx.x;
  int j = b >> 7;
  int xt = (b >> 4) & 7;
  int ht = b & 15;
  int x0 = xt << 6, h0 = ht << 6;
  int tid = threadIdx.x;
  int rp = tid >> 4;
  int cp = (tid & 15) << 2;
  const float* eB = eW1 + (size_t)j * (XD * HD);
#pragma unroll
  for (int p = 0; p < 4; ++p) {
    int x = rp + (p << 4);
    size_t gi = (size_t)(x0 + x) * HD + (h0 + cp);
    f32x4 e = *(const f32x4*)(eB + gi);
    f32x4 m = *(const f32x4*)(muW1 + gi);
    f32x4 s = *(const f32x4*)(sigW1 + gi);
#pragma unroll
    for (int i = 0; i < 4; ++i) sT[cp + i][x] = (bf16)(m[i] + e[i] * s[i]);
  }
  __syncthreads();
#pragma unroll
  for (int p = 0; p < 4; ++p) {
    int h = rp + (p << 4);
    bf16x4 v;
#pragma unroll
    for (int i = 0; i < 4; ++i) v[i] = sT[h][cp + i];
    *(bf16x4*)(W1T + (size_t)(j * HD + h0 + h) * XD + (x0 + cp)) = v;
  }
}

// ---- K1b: XBF, W2T, B1W, B2W
__global__ __launch_bounds__(256) void build_small(
    const float* __restrict__ x,
    const float* __restrict__ muW2, const float* __restrict__ sigW2,
    const float* __restrict__ eW2,
    const float* __restrict__ mub1, const float* __restrict__ sigb1,
    const float* __restrict__ eb1,
    const float* __restrict__ mub2, const float* __restrict__ sigb2,
    const float* __restrict__ eb2,
    bf16* __restrict__ XBF, bf16* __restrict__ W2T,
    float* __restrict__ B1W, float* __restrict__ B2W) {
  int i = blockIdx.x * 256 + threadIdx.x;
  const int c0 = NN * XD;
  const int c1 = J * YD * HD;
  const int c2 = J * HD;
  const int c3 = J * YD;
  if (i < c0) { XBF[i] = (bf16)x[i]; return; }
  i -= c0;
  if (i < c1) {
    int h = i & (HD - 1);
    int jy = i >> 10;
    int y = jy & 15;
    int j = jy >> 4;
    float mu = muW2[h * YD + y], sg = sigW2[h * YD + y];
    float e = eW2[((size_t)j * HD + h) * YD + y];
    W2T[i] = (bf16)(mu + e * sg);
    return;
  }
  i -= c1;
  if (i < c2) {
    int h = i & (HD - 1);
    B1W[i] = mub1[h] + eb1[i] * sigb1[h];
    return;
  }
  i -= c2;
  if (i < c3) {
    int y = i & 15;
    B2W[i] = mub2[y] + eb2[i] * sigb2[y];
  }
}

// ---- K2: fused GEMM1 + clip + GEMM2 + permutation scatter
// grid 512 (64 j x 8 n-tiles of 128), block 256 threads / 4 waves (1n x 4h),
// wave tile 128n x 64h (intensity 21.3, acc1[4][8]=128 f32 VGPR; 256-thread
// workgroup gets 240 VGPR -- R12 measured -- so no spill).
// LDS 80KB/block -> 2 BLOCKS/CU -> 8 waves/CU = 2/SIMD: one block's vmcnt+barrier
// drain overlaps the other block's MFMA phase (the m114 mechanism R12 lost).
// BK=32 with PAIRED-ROW layout (2 logical rows per 128B LDS row) so the proven
// 8-slot XOR swizzle survives; all LDS access patterns verified exact 2-way (free).
// LDS: sA dbuf 2x8KB @0, sB dbuf 2x16KB @16384, sH [128n][128h] 32KB @49152 = 81920B
__global__ __launch_bounds__(256)
void fused_mlp(
    const bf16* __restrict__ XBF, const bf16* __restrict__ W1T,
    const bf16* __restrict__ W2T, const float* __restrict__ B1W,
    const float* __restrict__ B2W, const float* __restrict__ permu,
    float* __restrict__ out) {
  extern __shared__ char smem[];          // 81920 bytes

  int bid = blockIdx.x;
  // XCD swizzle: XCD x gets j in [8x,8x+8), all 8 n-tiles of each j together
  int L = ((bid & 7) << 6) | (bid >> 3);
  int j = L >> 3;
  int n0 = (L & 7) << 7;                  // 128-row n tile

  int tid = threadIdx.x;
  int wid = tid >> 6;               // 0..3
  int lane = tid & 63;
  int l15 = lane & 15;
  int lg = lane >> 4;               // 0..3
  int wh = wid << 6;                // wave h offset in the 256-h panel

  const bf16* w1base = W1T + (size_t)j * (HD * XD);
  const bf16* w2g = W2T + (size_t)((j << 4) + l15) * HD;  // row y = l15
  bf16* sH = (bf16*)(smem + 49152);

  f32x4 acc2[2];
#pragma unroll
  for (int f = 0; f < 2; ++f)
#pragma unroll
    for (int r = 0; r < 4; ++r) acc2[f][r] = 0.0f;

  // stage step into buf d: sA = x rows [n0,n0+128), sB = W1T rows [hb*256,+256),
  // k cols [k0,k0+32). Paired-row: row pr = r>>1, 128B = {r even 64B | r odd 64B},
  // 16B slot s_log = ((r&1)<<2)|kchunk, physical = s_log ^ (pr&7).
  auto stage = [&](int d, int k0, int hb_) {
#pragma unroll
    for (int q = 0; q < 2; ++q) {         // sA: 8KB
      int doff = (q << 12) + (tid << 4);
      int pr = doff >> 7;
      int sl = ((doff >> 4) & 7) ^ (pr & 7);
      int n = (pr << 1) | (sl >> 2);
      int kc = sl & 3;
      gload16(XBF + (size_t)(n0 + n) * XD + k0 + (kc << 3),
              smem + d * 8192 + doff);
    }
#pragma unroll
    for (int q = 0; q < 4; ++q) {         // sB: 16KB
      int doff = (q << 12) + (tid << 4);
      int pr = doff >> 7;
      int sl = ((doff >> 4) & 7) ^ (pr & 7);
      int h = (pr << 1) | (sl >> 2);
      int kc = sl & 3;
      gload16(w1base + (size_t)((hb_ << 8) + h) * XD + k0 + (kc << 3),
              smem + 16384 + d * 16384 + doff);
    }
  };

  // prologue
  stage(0, 0, 0);
  asm volatile("s_waitcnt vmcnt(0)" ::: "memory");
  __builtin_amdgcn_s_barrier();

#pragma unroll 1
  for (int hb = 0; hb < 4; ++hb) {
    // acc1[fb][fa]: fb = h fragment (wave's 64h), fa = n fragment (128n)
    f32x4 acc1[4][8];
#pragma unroll
    for (int fb = 0; fb < 4; ++fb)
#pragma unroll
      for (int fa = 0; fa < 8; ++fa)
#pragma unroll
        for (int r = 0; r < 4; ++r) acc1[fb][fa][r] = 0.0f;

#pragma unroll 1
    for (int t = 0; t < 16; ++t) {
      int s = (hb << 4) + t;
      int cur = s & 1;
      // issue next stage; drained by the vmcnt(0) a full compute-phase later
      if (t < 15)           stage(cur ^ 1, (t + 1) << 5, hb);
      else if (hb < 3)      stage(cur ^ 1, 0, hb + 1);
      const char* a_d = smem + cur * 8192;
      const char* b_d = smem + 16384 + cur * 16384;
      bf16x8 af[8], bg[4];
#pragma unroll
      for (int fa = 0; fa < 8; ++fa) {
        int n = (fa << 4) + l15;
        int pr = n >> 1;
        int ph = (((n & 1) << 2) | lg) ^ (pr & 7);
        af[fa] = *(const bf16x8*)(a_d + (pr << 7) + (ph << 4));
      }
#pragma unroll
      for (int fb = 0; fb < 4; ++fb) {
        int h = wh + (fb << 4) + l15;
        int pr = h >> 1;
        int ph = (((h & 1) << 2) | lg) ^ (pr & 7);
        bg[fb] = *(const bf16x8*)(b_d + (pr << 7) + (ph << 4));
      }
      __builtin_amdgcn_s_setprio(1);
#pragma unroll
      for (int fb = 0; fb < 4; ++fb)
#pragma unroll
        for (int fa = 0; fa < 8; ++fa)
          acc1[fb][fa] = __builtin_amdgcn_mfma_f32_16x16x32_bf16(
              bg[fb], af[fa], acc1[fb][fa], 0, 0, 0);  // A=W1(h), B=x(n)
      __builtin_amdgcn_s_setprio(0);
      asm volatile("s_waitcnt vmcnt(0)" ::: "memory");
      __builtin_amdgcn_s_barrier();
    }

    // b1 for this wave's 64-h slice (f32x4 per fb; lg*4+r matches D rows)
    f32x4 b1v[4];
#pragma unroll
    for (int fb = 0; fb < 4; ++fb)
      b1v[fb] = *(const f32x4*)&B1W[(j << 10) + (hb << 8) + wh + (fb << 4) + (lg << 2)];

    // ---- 2 h-chunks of 128: waves (wid>>1)==c write their acc1 -> sH, all GEMM2
#pragma unroll 1
    for (int c = 0; c < 2; ++c) {
      __builtin_amdgcn_s_barrier();   // previous chunk's GEMM2 reads done
      bf16x8 wg[4];                   // W2 frags for this chunk (latency hidden)
#pragma unroll
      for (int kk2 = 0; kk2 < 4; ++kk2)
        wg[kk2] = *(const bf16x8*)(w2g + (hb << 8) + (c << 7) + (kk2 << 5) + (lg << 3));
      if ((wid >> 1) == c) {
#pragma unroll
        for (int fa = 0; fa < 8; ++fa)
#pragma unroll
          for (int fb = 0; fb < 4; ++fb) {
            bf16x4 pk;
#pragma unroll
            for (int r = 0; r < 4; ++r) {
              float v = acc1[fb][fa][r] + b1v[fb][r];
              v = fminf(1.0f, fmaxf(-1.0f, v));
              pk[r] = (bf16)v;
            }
            int n = (fa << 4) + l15;
            int hl = ((wid & 1) << 6) + (fb << 4) + (lg << 2);   // chunk-local h
            int byte = (n << 8) + ((hl << 1) ^ ((n & 7) << 4));
            *(bf16x4*)((char*)sH + byte) = pk;
          }
      }
      asm volatile("s_waitcnt lgkmcnt(0)" ::: "memory");
      __builtin_amdgcn_s_barrier();   // sH chunk visible
      // GEMM2: wave owns rows wid*32..+32 of 128
#pragma unroll
      for (int kk2 = 0; kk2 < 4; ++kk2) {
#pragma unroll
        for (int f = 0; f < 2; ++f) {
          int row = (wid << 5) + (f << 4) + l15;
          int cb = ((kk2 << 6) + (lg << 4)) ^ ((row & 7) << 4);
          bf16x8 hf = *(const bf16x8*)((char*)sH + (row << 8) + cb);
          acc2[f] = __builtin_amdgcn_mfma_f32_16x16x32_bf16(hf, wg[kk2], acc2[f], 0, 0, 0);
        }
      }
    }
  }

  // ---- epilogue: b2, stage out tile (reuses sA/sB region), permutation gather
  float b2v = B2W[(j << 4) + l15];
  float* sOut = (float*)smem;              // [128][17] f32 = 8704B
  int* sIdx = (int*)(smem + 20480);        // [128]
#pragma unroll
  for (int f = 0; f < 2; ++f)
#pragma unroll
    for (int r = 0; r < 4; ++r) {
      int row = (wid << 5) + (f << 4) + (lg << 2) + r;
      sOut[row * 17 + l15] = acc2[f][r] + b2v;
    }
  if (tid < 128) {  // cidx[p][y] = col c with permu[p][c][y]==1
    int p = tid >> 4, y = tid & 15;
    int c = 0;
#pragma unroll
    for (int cc = 0; cc < 16; ++cc)
      if (permu[((p << 4) + cc) * 16 + y] > 0.5f) c = cc;
    sIdx[tid] = c;
  }
  __syncthreads();
#pragma unroll 1
  for (int it = 0; it < 16; ++it) {
    int flat = (it << 10) + (tid << 2);   // p[3] n[7] y[4]
    int p = flat >> 11;
    int n = (flat >> 4) & 127;
    int y0 = flat & 15;
    f32x4 v;
#pragma unroll
    for (int q = 0; q < 4; ++q) v[q] = sOut[n * 17 + sIdx[(p << 4) + y0 + q]];
    *(f32x4*)(out + ((size_t)((j << 3) + p) * NN + n0 + n) * YD + y0) = v;
  }
}

extern "C" void kernel_launch(void* const* d_in, const int* in_sizes, int n_in,
                              void* d_out, int out_size, void* d_ws, size_t ws_size,
                              hipStream_t stream) {
  (void)in_sizes; (void)n_in; (void)out_size; (void)ws_size;
  const float* x      = (const float*)d_in[0];
  const float* mu_W1  = (const float*)d_in[1];
  const float* mu_b1  = (const float*)d_in[2];
  const float* mu_W2  = (const float*)d_in[3];
  const float* mu_b2  = (const float*)d_in[4];
  const float* sig_W1 = (const float*)d_in[5];
  const float* sig_b1 = (const float*)d_in[6];
  const float* sig_W2 = (const float*)d_in[7];
  const float* sig_b2 = (const float*)d_in[8];
  const float* e_W1   = (const float*)d_in[9];
  const float* e_b1   = (const float*)d_in[10];
  const float* e_W2   = (const float*)d_in[11];
  const float* e_b2   = (const float*)d_in[12];
  const float* permu  = (const float*)d_in[13];
  float* out = (float*)d_out;

  char* ws = (char*)d_ws;
  bf16* W1T = (bf16*)(ws);
  bf16* W2T = (bf16*)(ws + 67108864);
  bf16* XBF = (bf16*)(ws + 69206016);
  float* B1W = (float*)(ws + 70254592);
  float* B2W = (float*)(ws + 70516736);

  static int lds_set = 0;
  if (!lds_set) {  // R13 bug fix: 81920B dynamic LDS still needs the attribute
    hipFuncSetAttribute((const void*)fused_mlp,
                        hipFuncAttributeMaxDynamicSharedMemorySize, 81920);
    lds_set = 1;
  }

  build_w1t<<<dim3(8192), dim3(256), 0, stream>>>(mu_W1, sig_W1, e_W1, W1T);
  build_small<<<dim3(6404), dim3(256), 0, stream>>>(
      x, mu_W2, sig_W2, e_W2, mu_b1, sig_b1, e_b1, mu_b2, sig_b2, e_b2,
      XBF, W2T, B1W, B2W);
  fused_mlp<<<dim3(512), dim3(256), 81920, stream>>>(
      XBF, W1T, W2T, B1W, B2W, permu, out);
}

// Round 15
// 119.259 us; speedup vs baseline: 1.2359x; 1.2359x over previous
//
#include <hip/hip_runtime.h>
#include <cstdint>
#include <cstddef>

#define J 64
#define XD 512
#define HD 1024
#define YD 16
#define PP 8
#define NN 1024

typedef __bf16 bf16;
typedef __attribute__((ext_vector_type(8))) __bf16 bf16x8;
typedef __attribute__((ext_vector_type(4))) __bf16 bf16x4;
typedef __attribute__((ext_vector_type(4))) float f32x4;

__device__ __forceinline__ void gload16(const void* g, void* l) {
  __builtin_amdgcn_global_load_lds((__attribute__((address_space(1))) void*)(g),
                                   (__attribute__((address_space(3))) void*)(l),
                                   16, 0, 0);
}

// ---- K1 (merged): blocks [0,8192) build W1T; blocks [8192,14596) build the rest.
// Both paths are memory-bound and independent; merging saves a launch gap.
__global__ __launch_bounds__(256) void build_all(
    const float* __restrict__ muW1, const float* __restrict__ sigW1,
    const float* __restrict__ eW1, bf16* __restrict__ W1T,
    const float* __restrict__ x,
    const float* __restrict__ muW2, const float* __restrict__ sigW2,
    const float* __restrict__ eW2,
    const float* __restrict__ mub1, const float* __restrict__ sigb1,
    const float* __restrict__ eb1,
    const float* __restrict__ mub2, const float* __restrict__ sigb2,
    const float* __restrict__ eb2,
    bf16* __restrict__ XBF, bf16* __restrict__ W2T,
    float* __restrict__ B1W, float* __restrict__ B2W) {
  __shared__ bf16 sT[64][66];  // used only by the W1T path
  int b = blockIdx.x;
  int tid = threadIdx.x;
  if (b < 8192) {
    // W1T[j][h][x] = bf16(mu_W1[x][h] + e_W1[j][x][h]*sig_W1[x][h])
    int j = b >> 7;
    int xt = (b >> 4) & 7;
    int ht = b & 15;
    int x0 = xt << 6, h0 = ht << 6;
    int rp = tid >> 4;
    int cp = (tid & 15) << 2;
    const float* eB = eW1 + (size_t)j * (XD * HD);
#pragma unroll
    for (int p = 0; p < 4; ++p) {
      int xx = rp + (p << 4);
      size_t gi = (size_t)(x0 + xx) * HD + (h0 + cp);
      f32x4 e = *(const f32x4*)(eB + gi);
      f32x4 m = *(const f32x4*)(muW1 + gi);
      f32x4 s = *(const f32x4*)(sigW1 + gi);
#pragma unroll
      for (int i = 0; i < 4; ++i) sT[cp + i][xx] = (bf16)(m[i] + e[i] * s[i]);
    }
    __syncthreads();
#pragma unroll
    for (int p = 0; p < 4; ++p) {
      int h = rp + (p << 4);
      bf16x4 v;
#pragma unroll
      for (int i = 0; i < 4; ++i) v[i] = sT[h][cp + i];
      *(bf16x4*)(W1T + (size_t)(j * HD + h0 + h) * XD + (x0 + cp)) = v;
    }
    return;
  }
  int i = (b - 8192) * 256 + tid;
  const int c0 = NN * XD;        // 524288
  const int c1 = J * YD * HD;    // 1048576
  const int c2 = J * HD;         // 65536
  const int c3 = J * YD;         // 1024
  if (i < c0) { XBF[i] = (bf16)x[i]; return; }
  i -= c0;
  if (i < c1) {
    int h = i & (HD - 1);
    int jy = i >> 10;
    int y = jy & 15;
    int j = jy >> 4;
    float mu = muW2[h * YD + y], sg = sigW2[h * YD + y];
    float e = eW2[((size_t)j * HD + h) * YD + y];
    W2T[i] = (bf16)(mu + e * sg);
    return;
  }
  i -= c1;
  if (i < c2) {
    int h = i & (HD - 1);
    B1W[i] = mub1[h] + eb1[i] * sigb1[h];
    return;
  }
  i -= c2;
  if (i < c3) {
    int y = i & 15;
    B2W[i] = mub2[y] + eb2[i] * sigb2[y];
  }
}

// ---- K2: fused GEMM1 + clip + GEMM2 + permutation scatter
// R9-exact geometry/schedule (95.2us champion): 8 waves (4n x 2h), wave tile 64x64,
// BM=256 BN=128 BK=64, swapped-operand GEMM1, packed sH writes, VGPR~88.
// Single change vs R9: stage(t+1) issued AFTER kk=0's frag reads, so the
// latency-critical ds_reads hit the LDS pipe first after the barrier and the
// MFMA cluster starts sooner; stage's gload16s (latency-tolerant) fill in behind.
// LDS 160KB: sA dbuf 2x32KB @0, sB dbuf 2x16KB @65536, sH [256n][128h] 64KB @98304
__global__ __launch_bounds__(512)
__attribute__((amdgpu_waves_per_eu(2, 2)))
void fused_mlp(
    const bf16* __restrict__ XBF, const bf16* __restrict__ W1T,
    const bf16* __restrict__ W2T, const float* __restrict__ B1W,
    const float* __restrict__ B2W, const float* __restrict__ permu,
    float* __restrict__ out) {
  extern __shared__ char smem[];          // 163840 bytes

  int bid = blockIdx.x;
  // XCD swizzle: XCD x owns j in [8x,8x+8); each j's 4 n-tiles adjacent on one XCD
  int L = ((bid & 7) << 5) | (bid >> 3);
  int j = L >> 2;
  int n0 = (L & 3) << 8;

  int tid = threadIdx.x;
  int wid = tid >> 6;               // 0..7
  int lane = tid & 63;
  int l15 = lane & 15;
  int lg = lane >> 4;               // 0..3
  int wn = (wid >> 1) << 6;         // wave n offset (0,64,128,192)
  int wh = (wid & 1) << 6;          // wave h offset (0,64)
  int srow = tid >> 3;              // staging row 0..63 (+64 per q)
  int slot = tid & 7;               // staging 16B slot in 128B row

  const bf16* w1base = W1T + (size_t)j * (HD * XD);
  const bf16* w2g = W2T + (size_t)((j << 4) + l15) * HD;  // row y = l15
  bf16* sH = (bf16*)(smem + 98304);

  f32x4 acc2[2];
#pragma unroll
  for (int f = 0; f < 2; ++f)
#pragma unroll
    for (int r = 0; r < 4; ++r) acc2[f][r] = 0.0f;

  // stage into buf d: sA = x rows [n0, n0+256), sB = W1T rows [hb*128, +128)
  auto stage = [&](int d, int k0, int hb_) {
    char* aD = smem + d * 32768 + (tid << 4);
    char* bD = smem + 65536 + d * 16384 + (tid << 4);
#pragma unroll
    for (int q = 0; q < 4; ++q) {
      int r = (q << 6) + srow;
      int sc = slot ^ (r & 7);
      gload16(XBF + (size_t)(n0 + r) * XD + k0 + (sc << 3), aD + (q << 13));
      if (q < 2)
        gload16(w1base + (size_t)((hb_ << 7) + r) * XD + k0 + (sc << 3), bD + (q << 13));
    }
  };

  // prologue: stage (hb=0, t=0) into buf0
  stage(0, 0, 0);
  asm volatile("s_waitcnt vmcnt(0)" ::: "memory");
  __builtin_amdgcn_s_barrier();

#pragma unroll 1
  for (int hb = 0; hb < 8; ++hb) {
    // acc1[fb][fa]: fb = W1T(h) fragment, fa = x(n) fragment (swapped-operand MFMA)
    f32x4 acc1[4][4];
#pragma unroll
    for (int fb = 0; fb < 4; ++fb)
#pragma unroll
      for (int fa = 0; fa < 4; ++fa)
#pragma unroll
        for (int r = 0; r < 4; ++r) acc1[fb][fa][r] = 0.0f;

    int cur = 0;
#pragma unroll 1
    for (int t = 0; t < 8; ++t) {
      const char* a_d = smem + cur * 32768;
      const char* b_d = smem + 65536 + cur * 16384;
#pragma unroll
      for (int kk = 0; kk < 2; ++kk) {
        bf16x8 af[4], bg[4];
#pragma unroll
        for (int fa = 0; fa < 4; ++fa) {
          int ra = wn + (fa << 4) + l15;
          int ca = ((kk << 6) + (lg << 4)) ^ ((ra & 7) << 4);
          af[fa] = *(const bf16x8*)(a_d + (ra << 7) + ca);
        }
#pragma unroll
        for (int fb = 0; fb < 4; ++fb) {
          int rb = wh + (fb << 4) + l15;
          int cb = ((kk << 6) + (lg << 4)) ^ ((rb & 7) << 4);
          bg[fb] = *(const bf16x8*)(b_d + (rb << 7) + cb);
        }
        // stage issue AFTER the first frag-read burst, BEFORE the MFMA cluster:
        // reads own the LDS pipe right after the barrier; stage fills in behind.
        if (kk == 0) {
          if (t < 7)            stage(cur ^ 1, (t + 1) << 6, hb);
          else if (hb < 7)      stage(cur ^ 1, 0, hb + 1);
        }
        __builtin_amdgcn_s_setprio(1);
#pragma unroll
        for (int fb = 0; fb < 4; ++fb)
#pragma unroll
          for (int fa = 0; fa < 4; ++fa)
            acc1[fb][fa] = __builtin_amdgcn_mfma_f32_16x16x32_bf16(
                bg[fb], af[fa], acc1[fb][fa], 0, 0, 0);   // A=W1(h rows), B=x(n cols)
        __builtin_amdgcn_s_setprio(0);
      }
      asm volatile("s_waitcnt vmcnt(0)" ::: "memory");
      __builtin_amdgcn_s_barrier();
      cur ^= 1;
    }

    // W2 fragments for this hb (latency hidden under the sH-write phase)
    bf16x8 wg[4];
#pragma unroll
    for (int kk2 = 0; kk2 < 4; ++kk2)
      wg[kk2] = *(const bf16x8*)(w2g + (hb << 7) + (kk2 << 5) + (lg << 3));

    // ---- b1 + hardtanh -> sH [256 n][128 h], packed b64 writes
    // D layout: col(l15)=n-local, row(lg*4+r)=h-local -> r-consecutive = h-consecutive
    f32x4 b1v[4];
#pragma unroll
    for (int fb = 0; fb < 4; ++fb)
      b1v[fb] = *(const f32x4*)&B1W[(j << 10) + (hb << 7) + wh + (fb << 4) + (lg << 2)];
#pragma unroll
    for (int fa = 0; fa < 4; ++fa) {
#pragma unroll
      for (int fb = 0; fb < 4; ++fb) {
        bf16x4 pk;
#pragma unroll
        for (int r = 0; r < 4; ++r) {
          float v = acc1[fb][fa][r] + b1v[fb][r];
          v = fminf(1.0f, fmaxf(-1.0f, v));
          pk[r] = (bf16)v;
        }
        int n = wn + (fa << 4) + l15;
        int colb = (wh + (fb << 4) + (lg << 2)) << 1;       // byte col, 8B aligned
        int byte = (n << 8) + (colb ^ ((n & 7) << 4));
        *(bf16x4*)((char*)sH + byte) = pk;
      }
    }
    asm volatile("s_waitcnt lgkmcnt(0)" ::: "memory");  // sH writes retired
    __builtin_amdgcn_s_barrier();                       // sH visible to all waves
    // ---- GEMM2: wave owns rows wid*32..+32 of 256; W2 frags preloaded (wg)
#pragma unroll
    for (int kk2 = 0; kk2 < 4; ++kk2) {
#pragma unroll
      for (int f = 0; f < 2; ++f) {
        int row = (wid << 5) + (f << 4) + l15;
        int cb = ((kk2 << 6) + (lg << 4)) ^ ((row & 7) << 4);
        bf16x8 hf = *(const bf16x8*)((char*)sH + (row << 8) + cb);
        acc2[f] = __builtin_amdgcn_mfma_f32_16x16x32_bf16(hf, wg[kk2], acc2[f], 0, 0, 0);
      }
    }
    // no extra barrier: next sH write happens only after next hb's K-loop barriers
  }

  // ---- epilogue: b2, stage out tile (reuses sA region), permutation gather
  float b2v = B2W[(j << 4) + l15];
  float* sOut = (float*)smem;              // [256][17] f32 = 17408 B
  int* sIdx = (int*)(smem + 20480);        // [128]
#pragma unroll
  for (int f = 0; f < 2; ++f)
#pragma unroll
    for (int r = 0; r < 4; ++r) {
      int row = (wid << 5) + (f << 4) + (lg << 2) + r;
      sOut[row * 17 + l15] = acc2[f][r] + b2v;
    }
  if (tid < 128) {  // cidx[p][y] = c with permu[p][c][y]==1
    int p = tid >> 4, y = tid & 15;
    int c = 0;
#pragma unroll
    for (int cc = 0; cc < 16; ++cc)
      if (permu[((p << 4) + cc) * 16 + y] > 0.5f) c = cc;
    sIdx[tid] = c;
  }
  __syncthreads();
#pragma unroll 1
  for (int it = 0; it < 16; ++it) {
    int flat = (it << 11) + (tid << 2);   // p[3] n[8] y[4]
    int p = flat >> 12;
    int n = (flat >> 4) & 255;
    int y0 = flat & 15;
    f32x4 v;
#pragma unroll
    for (int q = 0; q < 4; ++q) v[q] = sOut[n * 17 + sIdx[(p << 4) + y0 + q]];
    *(f32x4*)(out + ((size_t)((j << 3) + p) * NN + n0 + n) * YD + y0) = v;
  }
}

extern "C" void kernel_launch(void* const* d_in, const int* in_sizes, int n_in,
                              void* d_out, int out_size, void* d_ws, size_t ws_size,
                              hipStream_t stream) {
  (void)in_sizes; (void)n_in; (void)out_size; (void)ws_size;
  const float* x      = (const float*)d_in[0];
  const float* mu_W1  = (const float*)d_in[1];
  const float* mu_b1  = (const float*)d_in[2];
  const float* mu_W2  = (const float*)d_in[3];
  const float* mu_b2  = (const float*)d_in[4];
  const float* sig_W1 = (const float*)d_in[5];
  const float* sig_b1 = (const float*)d_in[6];
  const float* sig_W2 = (const float*)d_in[7];
  const float* sig_b2 = (const float*)d_in[8];
  const float* e_W1   = (const float*)d_in[9];
  const float* e_b1   = (const float*)d_in[10];
  const float* e_W2   = (const float*)d_in[11];
  const float* e_b2   = (const float*)d_in[12];
  const float* permu  = (const float*)d_in[13];
  float* out = (float*)d_out;

  char* ws = (char*)d_ws;
  bf16* W1T = (bf16*)(ws);
  bf16* W2T = (bf16*)(ws + 67108864);
  bf16* XBF = (bf16*)(ws + 69206016);
  float* B1W = (float*)(ws + 70254592);
  float* B2W = (float*)(ws + 70516736);

  static int lds_set = 0;
  if (!lds_set) {  // idempotent host-side attribute; not a stream op (capture-safe)
    hipFuncSetAttribute((const void*)fused_mlp,
                        hipFuncAttributeMaxDynamicSharedMemorySize, 163840);
    lds_set = 1;
  }

  build_all<<<dim3(14596), dim3(256), 0, stream>>>(
      mu_W1, sig_W1, e_W1, W1T,
      x, mu_W2, sig_W2, e_W2, mu_b1, sig_b1, e_b1, mu_b2, sig_b2, e_b2,
      XBF, W2T, B1W, B2W);
  fused_mlp<<<dim3(256), dim3(512), 163840, stream>>>(
      XBF, W1T, W2T, B1W, B2W, permu, out);
}